// Round 7
// baseline (282.334 us; speedup 1.0000x reference)
//
#include <hip/hip_runtime.h>
#include <stdint.h>

#define B_ 8
#define S_ 1024
#define D_ 1024
#define H_ 16
#define DK_ 64
#define DV_ 64

typedef __attribute__((ext_vector_type(8))) short short8;
typedef __attribute__((ext_vector_type(4))) float f32x4;

__device__ __forceinline__ unsigned short f2bf(float f) {
  union { float f; unsigned u; } v; v.f = f;
  return (unsigned short)((v.u + 0x7fffu + ((v.u >> 16) & 1u)) >> 16);
}
__device__ __forceinline__ unsigned short f2bf_trunc(float f) {
  union { float f; unsigned u; } v; v.f = f;
  return (unsigned short)(v.u >> 16);
}

// async global->LDS, 16B per lane; LDS dest = wave-uniform base + lane*16
__device__ __forceinline__ void ld_lds16(const unsigned short* g, unsigned short* l) {
  __builtin_amdgcn_global_load_lds((const __attribute__((address_space(1))) void*)g,
                                   (__attribute__((address_space(3))) void*)l, 16, 0, 0);
}

// ---------------- fp32 -> bf16 convert (x), 4 elems/thread ----------------
__global__ __launch_bounds__(256) void cvt_bf16_kernel(const float* __restrict__ in,
                                                       unsigned short* __restrict__ out) {
  size_t i = ((size_t)blockIdx.x * 256 + threadIdx.x) * 4;
  float4 v = *(const float4*)(in + i);
  ushort4 o;
  o.x = f2bf(v.x); o.y = f2bf(v.y); o.z = f2bf(v.z); o.w = f2bf(v.w);
  *(ushort4*)(out + i) = o;
}

// ---- fused transpose of 4 weight mats 1024x1024 fp32 (K,N) -> bf16 (N,K) ----
__global__ __launch_bounds__(256) void transpose4_kernel(const float* __restrict__ W0,
                                                         const float* __restrict__ W1,
                                                         const float* __restrict__ W2,
                                                         const float* __restrict__ W3,
                                                         unsigned short* __restrict__ T0,
                                                         unsigned short* __restrict__ T1,
                                                         unsigned short* __restrict__ T2,
                                                         unsigned short* __restrict__ T3) {
  __shared__ __align__(16) unsigned short tl[64][65];
  const float* W; unsigned short* Wt;
  switch (blockIdx.z) {
    case 0: W = W0; Wt = T0; break;
    case 1: W = W1; Wt = T1; break;
    case 2: W = W2; Wt = T2; break;
    default: W = W3; Wt = T3; break;
  }
  const int x = threadIdx.x & 63;
  const int y4 = threadIdx.x >> 6;
  const int bn = blockIdx.x * 64;   // N base
  const int bk = blockIdx.y * 64;   // K base
  #pragma unroll
  for (int r = y4; r < 64; r += 4)
    tl[r][x] = f2bf(W[(size_t)(bk + r) * 1024 + bn + x]);
  __syncthreads();
  #pragma unroll
  for (int r = y4; r < 64; r += 4)
    Wt[(size_t)(bn + r) * 1024 + bk + x] = tl[x][r];
}

// ------- BK=32 staging: 128 rows x 32 cols bf16, plain row-major (stride 32
// shorts = conflict-optimal 8-phase for b128 frag reads). 2 slots/thread. -----
__device__ __forceinline__ void stage_tile32(const unsigned short* __restrict__ G,
                                             unsigned short* __restrict__ Ls,
                                             int t, int wslot, int K, int k0) {
  #pragma unroll
  for (int i = 0; i < 2; i++) {
    int s = i * 256 + t;
    int r = s >> 2, c = s & 3;
    ld_lds16(G + (size_t)r * K + k0 + c * 8, &Ls[(i * 256 + wslot) * 8]);
  }
}

// ---------------- BK=64 staging helper: XOR-swizzled tiles ----------------
__device__ __forceinline__ void stage_tile64(const unsigned short* __restrict__ G,
                                             unsigned short* __restrict__ Ls,
                                             int t, int wslot, size_t rowstride, int k0) {
  #pragma unroll
  for (int i = 0; i < 4; i++) {
    int s = i * 256 + t;
    int r = s >> 3, c = (s & 7) ^ (r & 7);
    ld_lds16(G + (size_t)r * rowstride + k0 + c * 8, &Ls[(i * 256 + wslot) * 8]);
  }
}

// ----- fused QKV GEMM (BK=32, double-buffered): A (8192x1024), Bt (3072x1024) -----
// Prefetch tile k+1 issued right after the barrier -> flies during compute-k.
// blockIdx.x 0..7  -> q, scaled by 0.125*log2(e); 8..15 -> k;
// 16..23 -> v (B,H,DV,S), transposed operands, mask folded in.
__global__ __launch_bounds__(256) void gemm_qkv(const unsigned short* __restrict__ A,
                                                const unsigned short* __restrict__ Bt,
                                                const float* __restrict__ bq,
                                                const float* __restrict__ bk,
                                                const float* __restrict__ bv,
                                                const int* __restrict__ masks,
                                                unsigned short* __restrict__ q,
                                                unsigned short* __restrict__ kk,
                                                unsigned short* __restrict__ vT) {
  const int K = 1024;
  __shared__ __align__(16) unsigned short As[2][128 * 32];
  __shared__ __align__(16) unsigned short Bs[2][128 * 32];
  const int t = threadIdx.x;
  const int wave = t >> 6, lane = t & 63;
  const int l15 = lane & 15, quad = lane >> 4;
  const int bm = blockIdx.y * 128, bn = blockIdx.x * 128;
  const int wm = (wave & 1) * 64, wn = (wave >> 1) * 64;
  const bool vsec = (blockIdx.x >= 16);
  const int wslot = (t & ~63);

  f32x4 acc[4][4] = {};
  const unsigned short* Ag = A + (size_t)bm * K;
  const unsigned short* Bg = Bt + (size_t)bn * K;

  stage_tile32(Ag, As[0], t, wslot, K, 0);
  stage_tile32(Bg, Bs[0], t, wslot, K, 0);

  for (int k = 0; k < 32; k++) {
    __syncthreads();   // drains vmcnt -> tile k visible; prior reads of buf k+1 done
    if (k < 31) {
      stage_tile32(Ag, As[(k + 1) & 1], t, wslot, K, (k + 1) * 32);
      stage_tile32(Bg, Bs[(k + 1) & 1], t, wslot, K, (k + 1) * 32);
    }
    const unsigned short* Ab = As[k & 1];
    const unsigned short* Bb = Bs[k & 1];
    short8 af[4], bf[4];
    #pragma unroll
    for (int mi = 0; mi < 4; mi++)
      af[mi] = *(const short8*)&Ab[(wm + mi * 16 + l15) * 32 + quad * 8];
    #pragma unroll
    for (int ni = 0; ni < 4; ni++)
      bf[ni] = *(const short8*)&Bb[(wn + ni * 16 + l15) * 32 + quad * 8];
    if (vsec) {
      #pragma unroll
      for (int mi = 0; mi < 4; mi++)
        #pragma unroll
        for (int ni = 0; ni < 4; ni++)
          acc[mi][ni] = __builtin_amdgcn_mfma_f32_16x16x32_bf16(bf[ni], af[mi], acc[mi][ni], 0, 0, 0);
    } else {
      #pragma unroll
      for (int mi = 0; mi < 4; mi++)
        #pragma unroll
        for (int ni = 0; ni < 4; ni++)
          acc[mi][ni] = __builtin_amdgcn_mfma_f32_16x16x32_bf16(af[mi], bf[ni], acc[mi][ni], 0, 0, 0);
    }
  }

  if (!vsec) {
    int sec = blockIdx.x >> 3;   // 0 -> q, 1 -> k
    const float* bsel = (sec == 0) ? bq : bk;
    unsigned short* dst = (sec == 0) ? q : kk;
    float scale = (sec == 0) ? 0.180336880f : 1.0f;  // 0.125*log2(e) folded into q
    #pragma unroll
    for (int ni = 0; ni < 4; ni++) {
      int c = ((bn & 1023) + wn + ni * 16 + l15);
      float bvv = bsel[c];
      int hh = c >> 6, d = c & 63;
      #pragma unroll
      for (int mi = 0; mi < 4; mi++) {
        int row0 = bm + wm + mi * 16 + quad * 4;
        #pragma unroll
        for (int r = 0; r < 4; r++) {
          int row = row0 + r;
          int b = row >> 10, s = row & 1023;
          dst[(((size_t)(b * H_ + hh)) * S_ + s) * DK_ + d] = f2bf((acc[mi][ni][r] + bvv) * scale);
        }
      }
    }
  } else {
    // transposed accum: lane l15 -> row (s), quad*4+r -> col (d); mask folded
    #pragma unroll
    for (int ni = 0; ni < 4; ni++) {
      int cbase = (bn & 1023) + wn + ni * 16;
      #pragma unroll
      for (int mi = 0; mi < 4; mi++) {
        int row = bm + wm + mi * 16 + l15;
        int b = row >> 10, s = row & 1023;
        float mf = (masks[b * S_ + s] != 0) ? 1.0f : 0.0f;
        #pragma unroll
        for (int r = 0; r < 4; r++) {
          int c = cbase + quad * 4 + r;
          int hh = c >> 6, d = c & 63;
          vT[(((size_t)(b * H_ + hh)) * DV_ + d) * S_ + s] = f2bf((acc[mi][ni][r] + bv[c]) * mf);
        }
      }
    }
  }
}

// ------- out GEMM (BK=64, control: unchanged): A bf16, Bt bf16 -> fp32 ------
__global__ __launch_bounds__(256) void gemm_out(const unsigned short* __restrict__ A,
                                                const unsigned short* __restrict__ Bt,
                                                const float* __restrict__ bias,
                                                float* __restrict__ Cout) {
  const int K = 1024, N = 1024;
  __shared__ __align__(16) unsigned short As[128 * 64];
  __shared__ __align__(16) unsigned short Bs[128 * 64];
  const int t = threadIdx.x;
  const int wave = t >> 6, lane = t & 63;
  const int l15 = lane & 15, quad = lane >> 4;
  const int l7 = l15 & 7;
  const int bm = blockIdx.y * 128, bn = blockIdx.x * 128;
  const int wm = (wave & 1) * 64, wn = (wave >> 1) * 64;
  const int wslot = (t & ~63);

  f32x4 acc[4][4] = {};
  const unsigned short* Ag = A + (size_t)bm * K;
  const unsigned short* Bg = Bt + (size_t)bn * K;

  for (int k0 = 0; k0 < K; k0 += 64) {
    __syncthreads();
    stage_tile64(Ag, As, t, wslot, K, k0);
    stage_tile64(Bg, Bs, t, wslot, K, k0);
    __syncthreads();
    #pragma unroll
    for (int kf = 0; kf < 2; kf++) {
      short8 af[4], bf[4];
      #pragma unroll
      for (int mi = 0; mi < 4; mi++)
        af[mi] = *(const short8*)&As[(wm + mi * 16 + l15) * 64 + (((kf << 2) | quad) ^ l7) * 8];
      #pragma unroll
      for (int ni = 0; ni < 4; ni++)
        bf[ni] = *(const short8*)&Bs[(wn + ni * 16 + l15) * 64 + (((kf << 2) | quad) ^ l7) * 8];
      #pragma unroll
      for (int mi = 0; mi < 4; mi++)
        #pragma unroll
        for (int ni = 0; ni < 4; ni++)
          acc[mi][ni] = __builtin_amdgcn_mfma_f32_16x16x32_bf16(af[mi], bf[ni], acc[mi][ni], 0, 0, 0);
    }
  }

  #pragma unroll
  for (int ni = 0; ni < 4; ni++) {
    int col = bn + wn + ni * 16 + l15;
    float bvv = bias[col];
    #pragma unroll
    for (int mi = 0; mi < 4; mi++) {
      int row0 = bm + wm + mi * 16 + quad * 4;
      #pragma unroll
      for (int r = 0; r < 4; r++)
        Cout[(size_t)(row0 + r) * N + col] = acc[mi][ni][r] + bvv;
    }
  }
}

// ------------------------- flash attention v2 -------------------------
// grid: (B*H, S/128) -- bh on x so all 8 qt-blocks of a bh share an XCD
// (linear%8 = bh%8 since gridDim.x=128 is a multiple of 8) -> K/V L2 reuse.
// QK^T computed transposed (swapped operands): P written as b64; mask+l-sum
// offloaded to MFMA via pre-masked V' and a mask row (l in acc col 0).
#define PLD 72
__global__ __launch_bounds__(256) void attn_kernel(const unsigned short* __restrict__ Q,
                                                   const unsigned short* __restrict__ Kb,
                                                   const unsigned short* __restrict__ Vt,
                                                   const int* __restrict__ masks,
                                                   unsigned short* __restrict__ O) {
  __shared__ __align__(16) unsigned short QP[128 * PLD];  // Q staged (stride 64), then P (stride 72)
  __shared__ __align__(16) unsigned short Ks[64 * 64];
  __shared__ __align__(16) unsigned short Vs[80 * 64];    // rows 0..63 V', row 64 mask
  const int t = threadIdx.x;
  const int wave = t >> 6, lane = t & 63;
  const int l15 = lane & 15, quad = lane >> 4;
  const int l7 = l15 & 7;
  const int bh = blockIdx.x;       // 0..127  (XCD-locality key)
  const int qt = blockIdx.y;       // 0..7
  const int b = bh >> 4, h = bh & 15;

  const unsigned short* Qg = Q + ((size_t)bh * S_ + qt * 128) * DK_;
  const unsigned short* Kg = Kb + (size_t)bh * S_ * DK_;
  const unsigned short* Vg = Vt + (size_t)bh * DV_ * S_;
  const int wslot = (t & ~63);

  #pragma unroll
  for (int i = 0; i < 4; i++) {
    int p = i * 256 + t;
    ld_lds16(Qg + (size_t)p * 8, &QP[(i * 256 + wslot) * 8]);
  }
  __syncthreads();   // Q visible

  // Q fragments (B-operand): rows = q, plain stride 64
  short8 aq[2][2];
  #pragma unroll
  for (int mb = 0; mb < 2; mb++)
    #pragma unroll
    for (int kf = 0; kf < 2; kf++)
      aq[mb][kf] = *(const short8*)&QP[(wave * 32 + mb * 16 + l15) * 64 + kf * 32 + quad * 8];

  f32x4 o_acc[2][5] = {};   // [mb][n]; n==4 is the l column (col 0 valid)

  for (int kt = 0; kt < 16; kt++) {
    __syncthreads();
    #pragma unroll
    for (int i = 0; i < 2; i++) {
      int p = i * 256 + t;
      int rk = p >> 3, ck = (p & 7) ^ (rk & 7);
      ld_lds16(Kg + ((size_t)(kt * 64 + rk)) * DK_ + ck * 8, &Ks[(i * 256 + wslot) * 8]);
      ld_lds16(Vg + (size_t)rk * S_ + kt * 64 + ck * 8, &Vs[(i * 256 + wslot) * 8]);
    }
    // mask row (row 64 of Vs, identity swizzle since 64&7==0)
    if (wave == 0)
      Vs[64 * 64 + lane] = (masks[b * S_ + kt * 64 + lane] != 0) ? (unsigned short)0x3F80 : (unsigned short)0;
    __syncthreads();

    // S^T = K·Q^T : lane l15 = q, quad*4+r = key (within 16-tile)
    f32x4 sc[2][4];
    #pragma unroll
    for (int n = 0; n < 4; n++) {
      short8 bk0 = *(const short8*)&Ks[(n * 16 + l15) * 64 + (quad ^ l7) * 8];
      short8 bk1 = *(const short8*)&Ks[(n * 16 + l15) * 64 + ((4 + quad) ^ l7) * 8];
      #pragma unroll
      for (int mb = 0; mb < 2; mb++) {
        f32x4 c = {};
        c = __builtin_amdgcn_mfma_f32_16x16x32_bf16(bk0, aq[mb][0], c, 0, 0, 0);
        c = __builtin_amdgcn_mfma_f32_16x16x32_bf16(bk1, aq[mb][1], c, 0, 0, 0);
        sc[mb][n] = c;
      }
    }
    // exp2 + packed b64 P write: P[q][key]
    #pragma unroll
    for (int mb = 0; mb < 2; mb++)
      #pragma unroll
      for (int n = 0; n < 4; n++) {
        ushort4 pk;
        pk.x = f2bf_trunc(exp2f(sc[mb][n][0]));
        pk.y = f2bf_trunc(exp2f(sc[mb][n][1]));
        pk.z = f2bf_trunc(exp2f(sc[mb][n][2]));
        pk.w = f2bf_trunc(exp2f(sc[mb][n][3]));
        *(ushort4*)&QP[(wave * 32 + mb * 16 + l15) * PLD + n * 16 + quad * 4] = pk;
      }
    // PV (+l): O[q][d] += P[q][key]·V'[key][d]; n=4 reads mask row -> l in col 0
    #pragma unroll
    for (int kf = 0; kf < 2; kf++) {
      short8 ap[2];
      #pragma unroll
      for (int mb = 0; mb < 2; mb++)
        ap[mb] = *(const short8*)&QP[(wave * 32 + mb * 16 + l15) * PLD + kf * 32 + quad * 8];
      #pragma unroll
      for (int n = 0; n < 5; n++) {
        short8 bv = *(const short8*)&Vs[(n * 16 + l15) * 64 + ((kf * 4 + quad) ^ l7) * 8];
        #pragma unroll
        for (int mb = 0; mb < 2; mb++)
          o_acc[mb][n] = __builtin_amdgcn_mfma_f32_16x16x32_bf16(ap[mb], bv, o_acc[mb][n], 0, 0, 0);
      }
    }
  }

  // epilogue: l lives in o_acc[mb][4][r] at l15==0 -> broadcast within quad
  #pragma unroll
  for (int mb = 0; mb < 2; mb++)
    #pragma unroll
    for (int r = 0; r < 4; r++) {
      float l = __shfl(o_acc[mb][4][r], lane & 48, 64);
      float inv = 1.0f / l;
      int qrow = qt * 128 + wave * 32 + mb * 16 + quad * 4 + r;
      #pragma unroll
      for (int n = 0; n < 4; n++) {
        int col = h * 64 + n * 16 + l15;
        O[((size_t)b * S_ + qrow) * D_ + col] = f2bf(o_acc[mb][n][r] * inv);
      }
    }
}

extern "C" void kernel_launch(void* const* d_in, const int* in_sizes, int n_in,
                              void* d_out, int out_size, void* d_ws, size_t ws_size,
                              hipStream_t stream) {
  (void)in_sizes; (void)n_in; (void)out_size; (void)ws_size;
  const float* x  = (const float*)d_in[0];
  const int* masks = (const int*)d_in[1];
  const float* Wq = (const float*)d_in[2];
  const float* bq = (const float*)d_in[3];
  const float* Wk = (const float*)d_in[4];
  const float* bk = (const float*)d_in[5];
  const float* Wv = (const float*)d_in[6];
  const float* bv = (const float*)d_in[7];
  const float* Wo = (const float*)d_in[8];
  const float* bo = (const float*)d_in[9];

  char* p = (char*)d_ws;
  unsigned short* xb    = (unsigned short*)p; p += (size_t)8192 * 1024 * 2;
  unsigned short* WqkvT = (unsigned short*)p; p += (size_t)3072 * 1024 * 2;
  unsigned short* WoT   = (unsigned short*)p; p += (size_t)1024 * 1024 * 2;
  unsigned short* q     = (unsigned short*)p; p += (size_t)8192 * 1024 * 2;
  unsigned short* kk    = (unsigned short*)p; p += (size_t)8192 * 1024 * 2;
  unsigned short* vT    = (unsigned short*)p; p += (size_t)8192 * 1024 * 2;
  unsigned short* at    = (unsigned short*)p; p += (size_t)8192 * 1024 * 2;

  cvt_bf16_kernel<<<8192, 256, 0, stream>>>(x, xb);
  transpose4_kernel<<<dim3(16, 16, 4), 256, 0, stream>>>(
      Wq, Wk, Wv, Wo,
      WqkvT, WqkvT + (size_t)1024 * 1024, WqkvT + (size_t)2048 * 1024, WoT);
  gemm_qkv<<<dim3(24, 64), 256, 0, stream>>>(xb, WqkvT, bq, bk, bv, masks, q, kk, vT);
  attn_kernel<<<dim3(128, 8), 256, 0, stream>>>(q, kk, vT, masks, at);
  gemm_out<<<dim3(8, 64), 256, 0, stream>>>(at, WoT, bo, (float*)d_out);
}

// Round 8
// 248.314 us; speedup vs baseline: 1.1370x; 1.1370x over previous
//
#include <hip/hip_runtime.h>
#include <stdint.h>

#define B_ 8
#define S_ 1024
#define D_ 1024
#define H_ 16
#define DK_ 64
#define DV_ 64

typedef __attribute__((ext_vector_type(8))) short short8;
typedef __attribute__((ext_vector_type(4))) float f32x4;

__device__ __forceinline__ unsigned short f2bf(float f) {
  union { float f; unsigned u; } v; v.f = f;
  return (unsigned short)((v.u + 0x7fffu + ((v.u >> 16) & 1u)) >> 16);
}
__device__ __forceinline__ unsigned short f2bf_trunc(float f) {
  union { float f; unsigned u; } v; v.f = f;
  return (unsigned short)(v.u >> 16);
}

// async global->LDS, 16B per lane; LDS dest = wave-uniform base + lane*16
__device__ __forceinline__ void ld_lds16(const unsigned short* g, unsigned short* l) {
  __builtin_amdgcn_global_load_lds((const __attribute__((address_space(1))) void*)g,
                                   (__attribute__((address_space(3))) void*)l, 16, 0, 0);
}

// -------- fused prep: x fp32->bf16 (z>=4) + 4 weight transposes (z<4) --------
// z 0..3: transpose W[z] (K,N) fp32 -> (N,K) bf16, 64x64 tile per block.
// z 4..35: cvt slice; block handles 1024 contiguous elems (256 thr x 4).
__global__ __launch_bounds__(256) void prep_kernel(const float* __restrict__ x,
                                                   unsigned short* __restrict__ xb,
                                                   const float* __restrict__ W0,
                                                   const float* __restrict__ W1,
                                                   const float* __restrict__ W2,
                                                   const float* __restrict__ W3,
                                                   unsigned short* __restrict__ T0,
                                                   unsigned short* __restrict__ T1,
                                                   unsigned short* __restrict__ T2,
                                                   unsigned short* __restrict__ T3) {
  const int z = blockIdx.z;
  if (z >= 4) {
    size_t blk = (size_t)(z - 4) * 256 + blockIdx.y * 16 + blockIdx.x;
    size_t i = (blk * 256 + threadIdx.x) * 4;
    float4 v = *(const float4*)(x + i);
    ushort4 o;
    o.x = f2bf(v.x); o.y = f2bf(v.y); o.z = f2bf(v.z); o.w = f2bf(v.w);
    *(ushort4*)(xb + i) = o;
    return;
  }
  __shared__ __align__(16) unsigned short tl[64][65];
  const float* W; unsigned short* Wt;
  switch (z) {
    case 0: W = W0; Wt = T0; break;
    case 1: W = W1; Wt = T1; break;
    case 2: W = W2; Wt = T2; break;
    default: W = W3; Wt = T3; break;
  }
  const int xx = threadIdx.x & 63;
  const int y4 = threadIdx.x >> 6;
  const int bn = blockIdx.x * 64;   // N base
  const int bk = blockIdx.y * 64;   // K base
  #pragma unroll
  for (int r = y4; r < 64; r += 4)
    tl[r][xx] = f2bf(W[(size_t)(bk + r) * 1024 + bn + xx]);
  __syncthreads();
  #pragma unroll
  for (int r = y4; r < 64; r += 4)
    Wt[(size_t)(bn + r) * 1024 + bk + xx] = tl[xx][r];
}

// ---------------- BK=64 staging helper: XOR-swizzled tiles ----------------
__device__ __forceinline__ void stage_tile64(const unsigned short* __restrict__ G,
                                             unsigned short* __restrict__ Ls,
                                             int t, int wslot, size_t rowstride, int k0) {
  #pragma unroll
  for (int i = 0; i < 4; i++) {
    int s = i * 256 + t;
    int r = s >> 3, c = (s & 7) ^ (r & 7);
    ld_lds16(G + (size_t)r * rowstride + k0 + c * 8, &Ls[(i * 256 + wslot) * 8]);
  }
}

// ------------- fused QKV GEMM (BK=64): A (8192x1024), Bt (3072x1024) -------
// blockIdx.x 0..7  -> q (B,H,S,DK) bf16, scaled by 0.125*log2(e)
// blockIdx.x 8..15 -> k (B,H,S,DK) bf16
// blockIdx.x 16..23-> v (B,H,DV,S) bf16, transposed operands, MASK FOLDED IN:
//                     V'[d][s] = (V[d][s]+bias)*mask[s]
__global__ __launch_bounds__(256) void gemm_qkv(const unsigned short* __restrict__ A,
                                                const unsigned short* __restrict__ Bt,
                                                const float* __restrict__ bq,
                                                const float* __restrict__ bk,
                                                const float* __restrict__ bv,
                                                const int* __restrict__ masks,
                                                unsigned short* __restrict__ q,
                                                unsigned short* __restrict__ kk,
                                                unsigned short* __restrict__ vT) {
  const int K = 1024;
  __shared__ __align__(16) unsigned short As[128 * 64];
  __shared__ __align__(16) unsigned short Bs[128 * 64];
  const int t = threadIdx.x;
  const int wave = t >> 6, lane = t & 63;
  const int l15 = lane & 15, quad = lane >> 4;
  const int l7 = l15 & 7;
  const int bm = blockIdx.y * 128, bn = blockIdx.x * 128;
  const int wm = (wave & 1) * 64, wn = (wave >> 1) * 64;
  const bool vsec = (blockIdx.x >= 16);
  const int wslot = (t & ~63);

  f32x4 acc[4][4] = {};
  const unsigned short* Ag = A + (size_t)bm * K;
  const unsigned short* Bg = Bt + (size_t)bn * K;

  for (int k0 = 0; k0 < K; k0 += 64) {
    __syncthreads();
    stage_tile64(Ag, As, t, wslot, K, k0);
    stage_tile64(Bg, Bs, t, wslot, K, k0);
    __syncthreads();
    #pragma unroll
    for (int kf = 0; kf < 2; kf++) {
      short8 af[4], bf[4];
      #pragma unroll
      for (int mi = 0; mi < 4; mi++)
        af[mi] = *(const short8*)&As[(wm + mi * 16 + l15) * 64 + (((kf << 2) | quad) ^ l7) * 8];
      #pragma unroll
      for (int ni = 0; ni < 4; ni++)
        bf[ni] = *(const short8*)&Bs[(wn + ni * 16 + l15) * 64 + (((kf << 2) | quad) ^ l7) * 8];
      if (vsec) {
        #pragma unroll
        for (int mi = 0; mi < 4; mi++)
          #pragma unroll
          for (int ni = 0; ni < 4; ni++)
            acc[mi][ni] = __builtin_amdgcn_mfma_f32_16x16x32_bf16(bf[ni], af[mi], acc[mi][ni], 0, 0, 0);
      } else {
        #pragma unroll
        for (int mi = 0; mi < 4; mi++)
          #pragma unroll
          for (int ni = 0; ni < 4; ni++)
            acc[mi][ni] = __builtin_amdgcn_mfma_f32_16x16x32_bf16(af[mi], bf[ni], acc[mi][ni], 0, 0, 0);
      }
    }
  }

  if (!vsec) {
    int sec = blockIdx.x >> 3;   // 0 -> q, 1 -> k
    const float* bsel = (sec == 0) ? bq : bk;
    unsigned short* dst = (sec == 0) ? q : kk;
    float scale = (sec == 0) ? 0.180336880f : 1.0f;  // 0.125*log2(e) folded into q
    #pragma unroll
    for (int ni = 0; ni < 4; ni++) {
      int c = ((bn & 1023) + wn + ni * 16 + l15);
      float bvv = bsel[c];
      int hh = c >> 6, d = c & 63;
      #pragma unroll
      for (int mi = 0; mi < 4; mi++) {
        int row0 = bm + wm + mi * 16 + quad * 4;
        #pragma unroll
        for (int r = 0; r < 4; r++) {
          int row = row0 + r;
          int b = row >> 10, s = row & 1023;
          dst[(((size_t)(b * H_ + hh)) * S_ + s) * DK_ + d] = f2bf((acc[mi][ni][r] + bvv) * scale);
        }
      }
    }
  } else {
    // transposed accum: lane l15 -> row (s), quad*4+r -> col (d); mask folded
    #pragma unroll
    for (int ni = 0; ni < 4; ni++) {
      int cbase = (bn & 1023) + wn + ni * 16;
      #pragma unroll
      for (int mi = 0; mi < 4; mi++) {
        int row = bm + wm + mi * 16 + l15;
        int b = row >> 10, s = row & 1023;
        float mf = (masks[b * S_ + s] != 0) ? 1.0f : 0.0f;
        #pragma unroll
        for (int r = 0; r < 4; r++) {
          int c = cbase + quad * 4 + r;
          int hh = c >> 6, d = c & 63;
          vT[(((size_t)(b * H_ + hh)) * DV_ + d) * S_ + s] = f2bf((acc[mi][ni][r] + bv[c]) * mf);
        }
      }
    }
  }
}

// ------- out GEMM (BK=64): A (8192x1024) bf16, Bt (1024x1024) -> fp32 ------
__global__ __launch_bounds__(256) void gemm_out(const unsigned short* __restrict__ A,
                                                const unsigned short* __restrict__ Bt,
                                                const float* __restrict__ bias,
                                                float* __restrict__ Cout) {
  const int K = 1024, N = 1024;
  __shared__ __align__(16) unsigned short As[128 * 64];
  __shared__ __align__(16) unsigned short Bs[128 * 64];
  const int t = threadIdx.x;
  const int wave = t >> 6, lane = t & 63;
  const int l15 = lane & 15, quad = lane >> 4;
  const int l7 = l15 & 7;
  const int bm = blockIdx.y * 128, bn = blockIdx.x * 128;
  const int wm = (wave & 1) * 64, wn = (wave >> 1) * 64;
  const int wslot = (t & ~63);

  f32x4 acc[4][4] = {};
  const unsigned short* Ag = A + (size_t)bm * K;
  const unsigned short* Bg = Bt + (size_t)bn * K;

  for (int k0 = 0; k0 < K; k0 += 64) {
    __syncthreads();
    stage_tile64(Ag, As, t, wslot, K, k0);
    stage_tile64(Bg, Bs, t, wslot, K, k0);
    __syncthreads();
    #pragma unroll
    for (int kf = 0; kf < 2; kf++) {
      short8 af[4], bf[4];
      #pragma unroll
      for (int mi = 0; mi < 4; mi++)
        af[mi] = *(const short8*)&As[(wm + mi * 16 + l15) * 64 + (((kf << 2) | quad) ^ l7) * 8];
      #pragma unroll
      for (int ni = 0; ni < 4; ni++)
        bf[ni] = *(const short8*)&Bs[(wn + ni * 16 + l15) * 64 + (((kf << 2) | quad) ^ l7) * 8];
      #pragma unroll
      for (int mi = 0; mi < 4; mi++)
        #pragma unroll
        for (int ni = 0; ni < 4; ni++)
          acc[mi][ni] = __builtin_amdgcn_mfma_f32_16x16x32_bf16(af[mi], bf[ni], acc[mi][ni], 0, 0, 0);
    }
  }

  #pragma unroll
  for (int ni = 0; ni < 4; ni++) {
    int col = bn + wn + ni * 16 + l15;
    float bvv = bias[col];
    #pragma unroll
    for (int mi = 0; mi < 4; mi++) {
      int row0 = bm + wm + mi * 16 + quad * 4;
      #pragma unroll
      for (int r = 0; r < 4; r++)
        Cout[(size_t)(row0 + r) * N + col] = acc[mi][ni][r] + bvv;
    }
  }
}

// ------------------------- flash attention v2 -------------------------
// grid: (B*H, S/128) -- bh on x so all 8 qt-blocks of a bh share an XCD
// (linear%8 = bh%8 since gridDim.x=128 is a multiple of 8) -> K/V L2 reuse.
// QK^T computed transposed (swapped operands): P written as b64; mask+l-sum
// offloaded to MFMA via pre-masked V' and a mask row (l in acc col 0).
#define PLD 72
__global__ __launch_bounds__(256) void attn_kernel(const unsigned short* __restrict__ Q,
                                                   const unsigned short* __restrict__ Kb,
                                                   const unsigned short* __restrict__ Vt,
                                                   const int* __restrict__ masks,
                                                   unsigned short* __restrict__ O) {
  __shared__ __align__(16) unsigned short QP[128 * PLD];  // Q staged (stride 64), then P (stride 72)
  __shared__ __align__(16) unsigned short Ks[64 * 64];
  __shared__ __align__(16) unsigned short Vs[80 * 64];    // rows 0..63 V', row 64 mask
  const int t = threadIdx.x;
  const int wave = t >> 6, lane = t & 63;
  const int l15 = lane & 15, quad = lane >> 4;
  const int l7 = l15 & 7;
  const int bh = blockIdx.x;       // 0..127  (XCD-locality key)
  const int qt = blockIdx.y;       // 0..7
  const int b = bh >> 4, h = bh & 15;

  const unsigned short* Qg = Q + ((size_t)bh * S_ + qt * 128) * DK_;
  const unsigned short* Kg = Kb + (size_t)bh * S_ * DK_;
  const unsigned short* Vg = Vt + (size_t)bh * DV_ * S_;
  const int wslot = (t & ~63);

  #pragma unroll
  for (int i = 0; i < 4; i++) {
    int p = i * 256 + t;
    ld_lds16(Qg + (size_t)p * 8, &QP[(i * 256 + wslot) * 8]);
  }
  __syncthreads();   // Q visible

  // Q fragments (B-operand): rows = q, plain stride 64
  short8 aq[2][2];
  #pragma unroll
  for (int mb = 0; mb < 2; mb++)
    #pragma unroll
    for (int kf = 0; kf < 2; kf++)
      aq[mb][kf] = *(const short8*)&QP[(wave * 32 + mb * 16 + l15) * 64 + kf * 32 + quad * 8];

  f32x4 o_acc[2][5] = {};   // [mb][n]; n==4 is the l column (col 0 valid)

  for (int kt = 0; kt < 16; kt++) {
    __syncthreads();
    #pragma unroll
    for (int i = 0; i < 2; i++) {
      int p = i * 256 + t;
      int rk = p >> 3, ck = (p & 7) ^ (rk & 7);
      ld_lds16(Kg + ((size_t)(kt * 64 + rk)) * DK_ + ck * 8, &Ks[(i * 256 + wslot) * 8]);
      ld_lds16(Vg + (size_t)rk * S_ + kt * 64 + ck * 8, &Vs[(i * 256 + wslot) * 8]);
    }
    // mask row (row 64 of Vs, identity swizzle since 64&7==0)
    if (wave == 0)
      Vs[64 * 64 + lane] = (masks[b * S_ + kt * 64 + lane] != 0) ? (unsigned short)0x3F80 : (unsigned short)0;
    __syncthreads();

    // S^T = K·Q^T : lane l15 = q, quad*4+r = key (within 16-tile)
    f32x4 sc[2][4];
    #pragma unroll
    for (int n = 0; n < 4; n++) {
      short8 bk0 = *(const short8*)&Ks[(n * 16 + l15) * 64 + (quad ^ l7) * 8];
      short8 bk1 = *(const short8*)&Ks[(n * 16 + l15) * 64 + ((4 + quad) ^ l7) * 8];
      #pragma unroll
      for (int mb = 0; mb < 2; mb++) {
        f32x4 c = {};
        c = __builtin_amdgcn_mfma_f32_16x16x32_bf16(bk0, aq[mb][0], c, 0, 0, 0);
        c = __builtin_amdgcn_mfma_f32_16x16x32_bf16(bk1, aq[mb][1], c, 0, 0, 0);
        sc[mb][n] = c;
      }
    }
    // exp2 + packed b64 P write: P[q][key]
    #pragma unroll
    for (int mb = 0; mb < 2; mb++)
      #pragma unroll
      for (int n = 0; n < 4; n++) {
        ushort4 pk;
        pk.x = f2bf_trunc(exp2f(sc[mb][n][0]));
        pk.y = f2bf_trunc(exp2f(sc[mb][n][1]));
        pk.z = f2bf_trunc(exp2f(sc[mb][n][2]));
        pk.w = f2bf_trunc(exp2f(sc[mb][n][3]));
        *(ushort4*)&QP[(wave * 32 + mb * 16 + l15) * PLD + n * 16 + quad * 4] = pk;
      }
    // PV (+l): O[q][d] += P[q][key]·V'[key][d]; n=4 reads mask row -> l in col 0
    #pragma unroll
    for (int kf = 0; kf < 2; kf++) {
      short8 ap[2];
      #pragma unroll
      for (int mb = 0; mb < 2; mb++)
        ap[mb] = *(const short8*)&QP[(wave * 32 + mb * 16 + l15) * PLD + kf * 32 + quad * 8];
      #pragma unroll
      for (int n = 0; n < 5; n++) {
        short8 bv = *(const short8*)&Vs[(n * 16 + l15) * 64 + ((kf * 4 + quad) ^ l7) * 8];
        #pragma unroll
        for (int mb = 0; mb < 2; mb++)
          o_acc[mb][n] = __builtin_amdgcn_mfma_f32_16x16x32_bf16(ap[mb], bv, o_acc[mb][n], 0, 0, 0);
      }
    }
  }

  // epilogue: l lives in o_acc[mb][4][r] at l15==0 -> broadcast within quad
  #pragma unroll
  for (int mb = 0; mb < 2; mb++)
    #pragma unroll
    for (int r = 0; r < 4; r++) {
      float l = __shfl(o_acc[mb][4][r], lane & 48, 64);
      float inv = 1.0f / l;
      int qrow = qt * 128 + wave * 32 + mb * 16 + quad * 4 + r;
      #pragma unroll
      for (int n = 0; n < 4; n++) {
        int col = h * 64 + n * 16 + l15;
        O[((size_t)b * S_ + qrow) * D_ + col] = f2bf(o_acc[mb][n][r] * inv);
      }
    }
}

extern "C" void kernel_launch(void* const* d_in, const int* in_sizes, int n_in,
                              void* d_out, int out_size, void* d_ws, size_t ws_size,
                              hipStream_t stream) {
  (void)in_sizes; (void)n_in; (void)out_size; (void)ws_size;
  const float* x  = (const float*)d_in[0];
  const int* masks = (const int*)d_in[1];
  const float* Wq = (const float*)d_in[2];
  const float* bq = (const float*)d_in[3];
  const float* Wk = (const float*)d_in[4];
  const float* bk = (const float*)d_in[5];
  const float* Wv = (const float*)d_in[6];
  const float* bv = (const float*)d_in[7];
  const float* Wo = (const float*)d_in[8];
  const float* bo = (const float*)d_in[9];

  char* p = (char*)d_ws;
  unsigned short* xb    = (unsigned short*)p; p += (size_t)8192 * 1024 * 2;
  unsigned short* WqkvT = (unsigned short*)p; p += (size_t)3072 * 1024 * 2;
  unsigned short* WoT   = (unsigned short*)p; p += (size_t)1024 * 1024 * 2;
  unsigned short* q     = (unsigned short*)p; p += (size_t)8192 * 1024 * 2;
  unsigned short* kk    = (unsigned short*)p; p += (size_t)8192 * 1024 * 2;
  unsigned short* vT    = (unsigned short*)p; p += (size_t)8192 * 1024 * 2;
  unsigned short* at    = (unsigned short*)p; p += (size_t)8192 * 1024 * 2;

  prep_kernel<<<dim3(16, 16, 36), 256, 0, stream>>>(
      x, xb, Wq, Wk, Wv, Wo,
      WqkvT, WqkvT + (size_t)1024 * 1024, WqkvT + (size_t)2048 * 1024, WoT);
  gemm_qkv<<<dim3(24, 64), 256, 0, stream>>>(xb, WqkvT, bq, bk, bv, masks, q, kk, vT);
  attn_kernel<<<dim3(128, 8), 256, 0, stream>>>(q, kk, vT, masks, at);
  gemm_out<<<dim3(8, 64), 256, 0, stream>>>(at, WoT, bo, (float*)d_out);
}